// Round 1
// baseline (2065.464 us; speedup 1.0000x reference)
//
#include <hip/hip_runtime.h>
#include <hip/hip_bf16.h>

#define D_DIM 768
#define BM 128
#define BN 128
#define BK 32

typedef __attribute__((ext_vector_type(8))) short short8;
typedef __attribute__((ext_vector_type(4))) float f32x4;

// round-to-nearest-even f32 -> bf16
__device__ __forceinline__ unsigned short f2bf(float f) {
  unsigned int u = __float_as_uint(f);
  u += 0x7fffu + ((u >> 16) & 1u);
  return (unsigned short)(u >> 16);
}

// async global->LDS, 16 bytes per lane. LDS dest must be wave-uniform base;
// HW scatters lane i at base + i*16.
__device__ __forceinline__ void async_load16(const void* g, void* l) {
  __builtin_amdgcn_global_load_lds(
      (const __attribute__((address_space(1))) unsigned int*)(uintptr_t)g,
      (__attribute__((address_space(3))) unsigned int*)(uintptr_t)l,
      16, 0, 0);
}

// One wave per row: L2-normalize a 768-float row, emit bf16 (RNE).
__global__ __launch_bounds__(256) void norm_bf16_kernel(
    const float* __restrict__ in, unsigned short* __restrict__ out, int nrows) {
  int wave = threadIdx.x >> 6;
  int lane = threadIdx.x & 63;
  int row = blockIdx.x * 4 + wave;
  if (row >= nrows) return;
  const float4* rin = (const float4*)(in + (size_t)row * D_DIM);
  float4 v[3];
  float ss = 0.f;
#pragma unroll
  for (int c = 0; c < 3; ++c) {
    v[c] = rin[lane + 64 * c];
    ss += v[c].x * v[c].x + v[c].y * v[c].y + v[c].z * v[c].z + v[c].w * v[c].w;
  }
#pragma unroll
  for (int m = 1; m < 64; m <<= 1) ss += __shfl_xor(ss, m, 64);
  float inv = 1.0f / fmaxf(sqrtf(ss), 1e-12f);
  ushort4* rout = (ushort4*)(out + (size_t)row * D_DIM);
#pragma unroll
  for (int c = 0; c < 3; ++c) {
    ushort4 u;
    u.x = f2bf(v[c].x * inv);
    u.y = f2bf(v[c].y * inv);
    u.z = f2bf(v[c].z * inv);
    u.w = f2bf(v[c].w * inv);
    rout[lane + 64 * c] = u;
  }
}

// 128x128 tile GEMM (bf16 MFMA 16x16x32), fused exp(l/T) and per-colblock
// row-sum partials. X:[M][768] bf16 row-major, C:[P][768] bf16 row-major.
// out[n][p] = exp(dot(X[n],C[p]) / T); sums2d[cb*M + n] = partial row sum.
__global__ __launch_bounds__(256) void gemm_exp_kernel(
    const unsigned short* __restrict__ X, const unsigned short* __restrict__ Cp,
    const float* __restrict__ tptr, float* __restrict__ out,
    float* __restrict__ sums2d, int M, int P) {
  __shared__ unsigned short As[BM * BK];  // 8 KB
  __shared__ unsigned short Bs[BN * BK];  // 8 KB
  __shared__ float part[2][BM];           // 1 KB

  const int tid = threadIdx.x;
  const int lane = tid & 63;
  const int wave = tid >> 6;
  const int wr = wave >> 1;  // wave row (0..1): 64-row strip
  const int wc = wave & 1;   // wave col (0..1): 64-col strip
  const int mbase = blockIdx.y * BM;
  const int pbase = blockIdx.x * BN;
  const int col = lane & 15;
  const int quad = lane >> 4;

  f32x4 acc[4][4] = {};

  // staging: chunk c in [0,512) covers 16 B each; row = c/4, k = (c&3)*8
  const int c0 = tid, c1 = tid + 256;
  const unsigned short* ag0 = X + (size_t)(mbase + (c0 >> 2)) * D_DIM + (c0 & 3) * 8;
  const unsigned short* ag1 = X + (size_t)(mbase + (c1 >> 2)) * D_DIM + (c1 & 3) * 8;
  const unsigned short* bg0 = Cp + (size_t)(pbase + (c0 >> 2)) * D_DIM + (c0 & 3) * 8;
  const unsigned short* bg1 = Cp + (size_t)(pbase + (c1 >> 2)) * D_DIM + (c1 & 3) * 8;
  // wave-uniform LDS bases (lane scatter is implicit, 16 B/lane)
  unsigned short* al0 = As + wave * 512;
  unsigned short* al1 = As + 2048 + wave * 512;
  unsigned short* bl0 = Bs + wave * 512;
  unsigned short* bl1 = Bs + 2048 + wave * 512;

  for (int kt = 0; kt < D_DIM; kt += BK) {
    __syncthreads();  // LDS free from previous iteration's reads
    async_load16(ag0 + kt, al0);
    async_load16(ag1 + kt, al1);
    async_load16(bg0 + kt, bl0);
    async_load16(bg1 + kt, bl1);
    __syncthreads();  // drains vmcnt -> staged data visible

    short8 a[4], b[4];
#pragma unroll
    for (int i = 0; i < 4; ++i)
      a[i] = *(const short8*)&As[(wr * 64 + i * 16 + col) * BK + quad * 8];
#pragma unroll
    for (int j = 0; j < 4; ++j)
      b[j] = *(const short8*)&Bs[(wc * 64 + j * 16 + col) * BK + quad * 8];
#pragma unroll
    for (int i = 0; i < 4; ++i)
#pragma unroll
      for (int j = 0; j < 4; ++j)
        acc[i][j] = __builtin_amdgcn_mfma_f32_16x16x32_bf16(a[i], b[j], acc[i][j], 0, 0, 0);
  }

  const float invT = 1.0f / tptr[0];  // LOGIT_SCALE = 1
  float rsum[4][4];
#pragma unroll
  for (int i = 0; i < 4; ++i)
#pragma unroll
    for (int r = 0; r < 4; ++r) rsum[i][r] = 0.f;

  // C/D layout: col = lane&15 (p), row = quad*4 + r (m)
#pragma unroll
  for (int i = 0; i < 4; ++i) {
#pragma unroll
    for (int j = 0; j < 4; ++j) {
#pragma unroll
      for (int r = 0; r < 4; ++r) {
        float e = __expf(acc[i][j][r] * invT);
        size_t m = (size_t)(mbase + wr * 64 + i * 16 + quad * 4 + r);
        out[m * (size_t)P + pbase + wc * 64 + j * 16 + col] = e;
        rsum[i][r] += e;
      }
    }
  }
  // reduce 16 cols per row across the 16-lane groups
#pragma unroll
  for (int i = 0; i < 4; ++i) {
#pragma unroll
    for (int r = 0; r < 4; ++r) {
      float s = rsum[i][r];
      s += __shfl_xor(s, 1, 16);
      s += __shfl_xor(s, 2, 16);
      s += __shfl_xor(s, 4, 16);
      s += __shfl_xor(s, 8, 16);
      if (col == 0) part[wc][wr * 64 + i * 16 + quad * 4 + r] = s;
    }
  }
  __syncthreads();
  if (tid < BM) {
    float s = part[0][tid] + part[1][tid];
    sums2d[(size_t)blockIdx.x * M + mbase + tid] = s;
  }
}

// One block per row: reduce 32 partials, scale the row in place.
__global__ __launch_bounds__(256) void norm_div_kernel(
    float* __restrict__ out, const float* __restrict__ sums2d, int M, int P,
    int nblk) {
  const int row = blockIdx.x;
  const int tid = threadIdx.x;
  __shared__ float sinv;
  if (tid < 64) {
    float s = (tid < nblk) ? sums2d[(size_t)tid * M + row] : 0.f;
#pragma unroll
    for (int m = 1; m < 64; m <<= 1) s += __shfl_xor(s, m, 64);
    if (tid == 0) sinv = 1.0f / s;
  }
  __syncthreads();
  const float inv = sinv;
  float4* o4 = (float4*)(out + (size_t)row * P);
#pragma unroll
  for (int c = 0; c < 4; ++c) {  // 4096/4 = 1024 = 256*4
    float4 v = o4[tid + 256 * c];
    v.x *= inv; v.y *= inv; v.z *= inv; v.w *= inv;
    o4[tid + 256 * c] = v;
  }
}

extern "C" void kernel_launch(void* const* d_in, const int* in_sizes, int n_in,
                              void* d_out, int out_size, void* d_ws, size_t ws_size,
                              hipStream_t stream) {
  const float* emb = (const float*)d_in[0];
  const float* proto = (const float*)d_in[1];
  const float* temp = (const float*)d_in[2];
  const int M = in_sizes[0] / D_DIM;  // 65536
  const int P = in_sizes[1] / D_DIM;  // 4096
  float* out = (float*)d_out;

  unsigned short* Xb = (unsigned short*)d_ws;           // M*768 bf16 = 100.7 MB
  unsigned short* Cb = Xb + (size_t)M * D_DIM;          // P*768 bf16 = 6.3 MB
  float* sums2d = (float*)(Cb + (size_t)P * D_DIM);     // (P/BN)*M f32 = 8.4 MB

  norm_bf16_kernel<<<M / 4, 256, 0, stream>>>(emb, Xb, M);
  norm_bf16_kernel<<<(P + 3) / 4, 256, 0, stream>>>(proto, Cb, P);
  dim3 grid(P / BN, M / BM);
  gemm_exp_kernel<<<grid, 256, 0, stream>>>(Xb, Cb, temp, out, sums2d, M, P);
  norm_div_kernel<<<M, 256, 0, stream>>>(out, sums2d, M, P, P / BN);
}